// Round 17
// baseline (60.220 us; speedup 1.0000x reference)
//
#include <hip/hip_runtime.h>

#define N_ROWS 14400
#define M_COLS 1600
#define KDIM   256
#define GRID_X 25           // 1600 / 64  (exact)
#define GRID_Y 225          // 14400 / 64 (exact)
#define NWG    (GRID_X * GRID_Y)   // 5625

typedef __attribute__((ext_vector_type(8))) short bf16x8;
typedef __attribute__((ext_vector_type(4))) float f32x4;

__device__ __forceinline__ short f2bf(float x) {
  union { float f; unsigned u; } v; v.f = x;
  unsigned r = v.u + 0x7FFFu + ((v.u >> 16) & 1u);   // RNE to bf16
  return (short)(r >> 16);
}

__device__ __forceinline__ void gload_lds16(const void* g, void* l) {
  __builtin_amdgcn_global_load_lds(
      (const __attribute__((address_space(1))) void*)g,
      (__attribute__((address_space(3))) void*)l, 16, 0, 0);
}

// One WAVE per row; lane handles 4 consecutive floats (float4 in, short4 out).
__global__ __launch_bounds__(256) void prep_kernel(
    const float* __restrict__ logits, const float* __restrict__ embs,
    short* __restrict__ probB, short* __restrict__ embB) {
  const int row = blockIdx.x * 4 + (threadIdx.x >> 6);
  const int lane = threadIdx.x & 63;
  if (row < N_ROWS) {
    const float4 x = ((const float4*)(logits + (size_t)row * KDIM))[lane];
    float s = x.x * x.x + x.y * x.y + x.z * x.z + x.w * x.w;
#pragma unroll
    for (int o = 32; o > 0; o >>= 1) s += __shfl_xor(s, o, 64);
    const float scale = __builtin_amdgcn_rsqf(s);
    short4 o4;
    o4.x = f2bf(x.x * scale); o4.y = f2bf(x.y * scale);
    o4.z = f2bf(x.z * scale); o4.w = f2bf(x.w * scale);
    ((short4*)(probB + (size_t)row * KDIM))[lane] = o4;
  } else {
    const int r = row - N_ROWS;   // grid sized exactly, no overflow
    const float4 x = ((const float4*)(embs + (size_t)r * KDIM))[lane];
    short4 o4;
    o4.x = f2bf(x.x); o4.y = f2bf(x.y); o4.z = f2bf(x.z); o4.w = f2bf(x.w);
    ((short4*)(embB + (size_t)r * KDIM))[lane] = o4;
  }
}

// 64x64 tile, FULL-K single-stage GEMM + fused epilogue.
// r17: stage the ENTIRE 64x256 A and B panels (64 KB LDS) in one burst of
// 16 gload_lds16/thread -> ONE __syncthreads -> 8 uninterrupted MFMA phases
// -> lgkm barrier -> single-pass epilogue -> 1 barrier -> NT stores.
// Barriers/block: 11 (r14) -> 3. The one vmcnt drain/block hides under the
// co-resident block's ~1000-cyc epilogue (inter-block TLP), unlike the 4
// failed intra-block pipelining attempts (r8/r10/r12/r15).
// - 512-B LDS rows: bank = (granule*4)%32, row-independent -> XOR swizzle
//   src granule (lane&31)^(row&7), read granule g^(row&7) -> 2-way (free).
// - acc[2][2] = 16 AGPR; exact 64-tiling (zero guards).
// - LDS 68 KB -> 2 blocks/CU (8 waves) - the experiment's main risk.
// - Epilogue: single-pass 64x68-pad tbuf overlay on dead As; 256-B-coalesced
//   dwordx4 NT stores, never drained mid-epilogue.
// - Bijective XCD swizzle; no launch clamp (r2/r4/r10 lesson).
__global__ __launch_bounds__(256) void cost_kernel(
    const short* __restrict__ probB, const short* __restrict__ embB,
    const float* __restrict__ pbox, const float* __restrict__ tbox,
    float* __restrict__ out) {
  __shared__ short As[64 * 256];    // 32 KB; tbuf (17 KB) overlays in epilogue
  __shared__ short Bs[64 * 256];    // 32 KB
  __shared__ f32x4 rowcc[64], rowxy[64];   // 2 KB
  __shared__ f32x4 colcc[64], colxy[64];   // 2 KB
  float* const tbuf = (float*)As;   // [64][68] f32

  const int t = threadIdx.x;
  const int lane = t & 63;
  const int wid = t >> 6;
  const int wr = wid >> 1;          // wave row 0..1 (32-row band)
  const int wc = wid & 1;           // wave col 0..1 (32-col band)

  // Bijective XCD swizzle (m204): 8 XCDs, NWG=5625 (q=703, r=1).
  const int orig = blockIdx.x;
  const int xcd = orig & 7;
  const int rem = orig >> 3;
  const int q = NWG >> 3, r = NWG & 7;
  const int wgid = (xcd < r ? xcd * (q + 1) : r * (q + 1) + (xcd - r) * q) + rem;
  const int bx = wgid % GRID_X;
  const int by = wgid / GRID_X;
  const int rowBase = by * 64;      // N (pred): always in-range (225*64)
  const int colBase = bx * 64;      // M (tgt):  always in-range (25*64)

  // Stage per-tile box data (no clamps: exact tiling).
  if (t < 64) {
    const float4 bb = ((const float4*)pbox)[rowBase + t];
    rowcc[t] = (f32x4){bb.x, bb.y, bb.z, bb.w};
    rowxy[t] = (f32x4){fmaf(-0.5f, bb.z, bb.x), fmaf(-0.5f, bb.w, bb.y),
                       fmaf(0.5f, bb.z, bb.x), fmaf(0.5f, bb.w, bb.y)};
  } else if (t < 128) {
    const int c = t - 64;
    const float4 bb = ((const float4*)tbox)[colBase + c];
    colcc[c] = (f32x4){bb.x, bb.y, bb.z, bb.w};
    colxy[c] = (f32x4){fmaf(-0.5f, bb.z, bb.x), fmaf(-0.5f, bb.w, bb.y),
                       fmaf(0.5f, bb.z, bb.x), fmaf(0.5f, bb.w, bb.y)};
  }

  f32x4 acc[2][2];
#pragma unroll
  for (int i = 0; i < 2; ++i)
#pragma unroll
    for (int j = 0; j < 2; ++j) acc[i][j] = (f32x4){0.f, 0.f, 0.f, 0.f};

  // Full-K staging: per round, each wave writes 1 KB linear LDS = 2 rows of
  // 512 B; lane covers row (lane>>5), granule (lane&31). Source granule is
  // pre-swizzled (lane&31)^(row&7) so swizzled reads see linear data.
  {
    const int lrow = lane >> 5;              // 0..1 within wave's 2 rows
    const int lgran = lane & 31;             // 16-B granule 0..31
#pragma unroll
    for (int ri = 0; ri < 8; ++ri) {
      const int rloc = ri * 8 + wid * 2 + lrow;       // 0..63
      const int gsrc = lgran ^ (rloc & 7);
      gload_lds16(probB + (size_t)(rowBase + rloc) * KDIM + gsrc * 8,
                  As + (ri * 8 + wid * 2) * 256);
    }
#pragma unroll
    for (int ri = 0; ri < 8; ++ri) {
      const int rloc = ri * 8 + wid * 2 + lrow;
      const int gsrc = lgran ^ (rloc & 7);
      gload_lds16(embB + (size_t)(colBase + rloc) * KDIM + gsrc * 8,
                  Bs + (ri * 8 + wid * 2) * 256);
    }
  }
  __syncthreads();   // the ONE vmcnt drain; also covers box-LDS writes

  // 8 uninterrupted MFMA phases (K = 8 x 32), no barriers.
#pragma unroll 2
  for (int kk = 0; kk < 8; ++kk) {
    bf16x8 af[2], bfr[2];
    const int g = kk * 4 + (lane >> 4);      // granule 0..31
#pragma unroll
    for (int mi = 0; mi < 2; ++mi) {
      const int row = wr * 32 + mi * 16 + (lane & 15);
      af[mi] = *(const bf16x8*)(As + row * 256 + ((g ^ (row & 7)) * 8));
    }
#pragma unroll
    for (int ni = 0; ni < 2; ++ni) {
      const int row = wc * 32 + ni * 16 + (lane & 15);
      bfr[ni] = *(const bf16x8*)(Bs + row * 256 + ((g ^ (row & 7)) * 8));
    }
#pragma unroll
    for (int mi = 0; mi < 2; ++mi)
#pragma unroll
      for (int ni = 0; ni < 2; ++ni)
        acc[mi][ni] = __builtin_amdgcn_mfma_f32_16x16x32_bf16(
            af[mi], bfr[ni], acc[mi][ni], 0, 0, 0);
  }
  // All waves done reading As/Bs before tbuf overlay.
  asm volatile("s_waitcnt lgkmcnt(0)" ::: "memory");
  __builtin_amdgcn_s_barrier();

  // Single-pass fused epilogue -> 64x68 tbuf -> 1 barrier -> NT stores.
  const float LOG2E = 1.44269504f;
  const int jr = (lane >> 4) * 4;
  const int lc = lane & 15;
  f32x4 c0v[2], c1v[2];
  float cav[2];
#pragma unroll
  for (int ni = 0; ni < 2; ++ni) {
    const int cloc = wc * 32 + ni * 16 + lc;
    c0v[ni] = colcc[cloc];
    c1v[ni] = colxy[cloc];
    cav[ni] = c0v[ni][2] * c0v[ni][3];
  }

#pragma unroll
  for (int mi = 0; mi < 2; ++mi) {
#pragma unroll
    for (int j = 0; j < 4; ++j) {
      const int row = wr * 32 + mi * 16 + jr + j;
      const f32x4 r0 = rowcc[row];
      const f32x4 r1 = rowxy[row];
      const float ra = r0[2] * r0[3];
#pragma unroll
      for (int ni = 0; ni < 2; ++ni) {
        const f32x4 c0 = c0v[ni], c1 = c1v[ni];
        const float cc = fmaxf(acc[mi][ni][j], 0.0f);
        const float l1 = fabsf(r0[0] - c0[0]) + fabsf(r0[1] - c0[1]) +
                         fabsf(r0[2] - c0[2]) + fabsf(r0[3] - c0[3]);
        const float iwx = fminf(r1[2], c1[2]) - fmaxf(r1[0], c1[0]);
        const float iwy = fminf(r1[3], c1[3]) - fmaxf(r1[1], c1[1]);
        const float iw = fmaxf(iwx, 0.f);
        const float ih = fmaxf(iwy, 0.f);
        const float inter = iw * ih;
        const float uni = ra + cav[ni] - inter;
        const float ex = (r0[2] + c0[2]) - iwx;
        const float ey = (r0[3] + c0[3]) - iwy;
        const float earea = ex * ey;
        const float num = fmaf(uni, uni, inter * earea);
        const float Cv = fmaf(-num, __builtin_amdgcn_rcpf(uni * earea),
                              l1 + cc + 1.0f);
        const float sg = __builtin_amdgcn_rcpf(
            1.0f + __builtin_amdgcn_exp2f(-LOG2E * Cv));
        tbuf[row * 68 + wc * 32 + ni * 16 + lc] = sg;
      }
    }
  }
  // lgkm-only barrier: LDS writes visible; NT stores stream undrained.
  asm volatile("s_waitcnt lgkmcnt(0)" ::: "memory");
  __builtin_amdgcn_s_barrier();
#pragma unroll
  for (int rr = 0; rr < 4; ++rr) {
    const int row = rr * 16 + (t >> 4);
    const int col = (t & 15) * 4;
    const f32x4 v = *(const f32x4*)(tbuf + row * 68 + col);
    __builtin_nontemporal_store(
        v, (f32x4*)(out + (size_t)(rowBase + row) * M_COLS + colBase + col));
  }
}

extern "C" void kernel_launch(void* const* d_in, const int* in_sizes, int n_in,
                              void* d_out, int out_size, void* d_ws, size_t ws_size,
                              hipStream_t stream) {
  const float* logits = (const float*)d_in[0];   // [16,900,256]
  const float* pbox   = (const float*)d_in[1];   // [16,900,4]
  const float* embs   = (const float*)d_in[2];   // [1600,256]
  const float* tbox   = (const float*)d_in[3];   // [1600,4]
  float* out = (float*)d_out;                    // [16,900,1600]

  short* probB = (short*)d_ws;                         // 14400*256 bf16
  short* embB  = probB + (size_t)N_ROWS * KDIM;        // 1600*256 bf16

  prep_kernel<<<(N_ROWS + M_COLS) / 4, 256, 0, stream>>>(logits, embs, probB, embB);

  cost_kernel<<<NWG, 256, 0, stream>>>(probB, embB, pbox, tbox, out);
}

// Round 18
// 48.209 us; speedup vs baseline: 1.2491x; 1.2491x over previous
//
#include <hip/hip_runtime.h>

#define N_ROWS 14400
#define M_COLS 1600
#define KDIM   256
#define GRID_X 25           // 1600 / 64  (exact)
#define GRID_Y 225          // 14400 / 64 (exact)
#define NWG    (GRID_X * GRID_Y)   // 5625

typedef __attribute__((ext_vector_type(8))) short bf16x8;
typedef __attribute__((ext_vector_type(4))) float f32x4;

__device__ __forceinline__ short f2bf(float x) {
  union { float f; unsigned u; } v; v.f = x;
  unsigned r = v.u + 0x7FFFu + ((v.u >> 16) & 1u);   // RNE to bf16
  return (short)(r >> 16);
}

__device__ __forceinline__ void gload_lds16(const void* g, void* l) {
  __builtin_amdgcn_global_load_lds(
      (const __attribute__((address_space(1))) void*)g,
      (__attribute__((address_space(3))) void*)l, 16, 0, 0);
}

// One WAVE per row; lane handles 4 consecutive floats (float4 in, short4 out).
__global__ __launch_bounds__(256) void prep_kernel(
    const float* __restrict__ logits, const float* __restrict__ embs,
    short* __restrict__ probB, short* __restrict__ embB) {
  const int row = blockIdx.x * 4 + (threadIdx.x >> 6);
  const int lane = threadIdx.x & 63;
  if (row < N_ROWS) {
    const float4 x = ((const float4*)(logits + (size_t)row * KDIM))[lane];
    float s = x.x * x.x + x.y * x.y + x.z * x.z + x.w * x.w;
#pragma unroll
    for (int o = 32; o > 0; o >>= 1) s += __shfl_xor(s, o, 64);
    const float scale = __builtin_amdgcn_rsqf(s);
    short4 o4;
    o4.x = f2bf(x.x * scale); o4.y = f2bf(x.y * scale);
    o4.z = f2bf(x.z * scale); o4.w = f2bf(x.w * scale);
    ((short4*)(probB + (size_t)row * KDIM))[lane] = o4;
  } else {
    const int r = row - N_ROWS;   // grid sized exactly, no overflow
    const float4 x = ((const float4*)(embs + (size_t)r * KDIM))[lane];
    short4 o4;
    o4.x = f2bf(x.x); o4.y = f2bf(x.y); o4.z = f2bf(x.z); o4.w = f2bf(x.w);
    ((short4*)(embB + (size_t)r * KDIM))[lane] = o4;
  }
}

// 64x64 tile GEMM (bf16 MFMA) + fused bbox-L1 + GIoU + sigmoid epilogue.
// r18 = r14 (best, 47.5us) with the mid-epilogue barrier removed:
// - Pass 0 transposes through the dead-As region, pass 1 through dead-Bs
//   ([32][64] f32 = 8 KB each, exact fit) -> no overwrite hazard -> the
//   barrier between pass-0 readback and pass-1 writes is gone (3 -> 2).
// - Stride-64 tbuf: writes 2-way bank-aliased (free, m136), readback phases
//   conflict-free, NT stores stay 256-B coalesced and are never drained.
// - K-loop/GEMM byte-identical to r14. Eight structural restructures
//   (r8/r10/r12/r13/r15/r16/r17 + r6) ALL lost to this naive loop at max
//   residency; do not touch it.
// - acc[2][2] = 16 AGPR; exact 64-tiling (zero guards); LDS 20 KB;
//   XOR-swizzled GEMM tiles -> 0 conflicts; bijective XCD swizzle;
//   no launch clamp (r2/r4/r10: forced VGPR<=64 always lost ~10us).
__global__ __launch_bounds__(256) void cost_kernel(
    const short* __restrict__ probB, const short* __restrict__ embB,
    const float* __restrict__ pbox, const float* __restrict__ tbox,
    float* __restrict__ out) {
  __shared__ short As[64 * 64];     // 8 KB; pass-0 tbuf overlay
  __shared__ short Bs[64 * 64];     // 8 KB; pass-1 tbuf overlay
  __shared__ f32x4 rowcc[64], rowxy[64];   // 2 KB
  __shared__ f32x4 colcc[64], colxy[64];   // 2 KB

  const int t = threadIdx.x;
  const int lane = t & 63;
  const int wid = t >> 6;
  const int wr = wid >> 1;          // wave row 0..1 (32-row band)
  const int wc = wid & 1;           // wave col 0..1 (32-col band)

  // Bijective XCD swizzle (m204): 8 XCDs, NWG=5625 (q=703, r=1).
  const int orig = blockIdx.x;
  const int xcd = orig & 7;
  const int rem = orig >> 3;
  const int q = NWG >> 3, r = NWG & 7;
  const int wgid = (xcd < r ? xcd * (q + 1) : r * (q + 1) + (xcd - r) * q) + rem;
  const int bx = wgid % GRID_X;
  const int by = wgid / GRID_X;
  const int rowBase = by * 64;      // N (pred): always in-range (225*64)
  const int colBase = bx * 64;      // M (tgt):  always in-range (25*64)

  // Stage per-tile box data (no clamps: exact tiling).
  if (t < 64) {
    const float4 bb = ((const float4*)pbox)[rowBase + t];
    rowcc[t] = (f32x4){bb.x, bb.y, bb.z, bb.w};
    rowxy[t] = (f32x4){fmaf(-0.5f, bb.z, bb.x), fmaf(-0.5f, bb.w, bb.y),
                       fmaf(0.5f, bb.z, bb.x), fmaf(0.5f, bb.w, bb.y)};
  } else if (t < 128) {
    const int c = t - 64;
    const float4 bb = ((const float4*)tbox)[colBase + c];
    colcc[c] = (f32x4){bb.x, bb.y, bb.z, bb.w};
    colxy[c] = (f32x4){fmaf(-0.5f, bb.z, bb.x), fmaf(-0.5f, bb.w, bb.y),
                       fmaf(0.5f, bb.z, bb.x), fmaf(0.5f, bb.w, bb.y)};
  }

  f32x4 acc[2][2];
#pragma unroll
  for (int i = 0; i < 2; ++i)
#pragma unroll
    for (int j = 0; j < 2; ++j) acc[i][j] = (f32x4){0.f, 0.f, 0.f, 0.f};

  // Pre-swizzled source granule: lane l stages granule (l&7)^(l>>3); read
  // slot g^(row&7) sees linear data.
  const int swz = (lane & 7) ^ (lane >> 3);
  const int rbase = wid * 8 + (lane >> 3);   // staging row within 32-row group

  // K-loop: 4 tiles of BK=64 (r14 verbatim).
  for (int kt = 0; kt < 4; ++kt) {
    const int k0 = kt * 64 + swz * 8;
#pragma unroll
    for (int i = 0; i < 2; ++i) {            // A: 64 rows
      const int gr = rowBase + i * 32 + rbase;
      gload_lds16(probB + (size_t)gr * KDIM + k0, As + (i * 32 + wid * 8) * 64);
    }
#pragma unroll
    for (int i = 0; i < 2; ++i) {            // B: 64 rows (cols)
      const int gc = colBase + i * 32 + rbase;
      gload_lds16(embB + (size_t)gc * KDIM + k0, Bs + (i * 32 + wid * 8) * 64);
    }
    __syncthreads();
#pragma unroll
    for (int kk = 0; kk < 2; ++kk) {
      bf16x8 af[2], bfr[2];
      const int g = kk * 4 + (lane >> 4);    // 16B granule index 0..7
#pragma unroll
      for (int mi = 0; mi < 2; ++mi) {
        const int row = wr * 32 + mi * 16 + (lane & 15);
        af[mi] = *(const bf16x8*)(As + row * 64 + ((g ^ (row & 7)) * 8));
      }
#pragma unroll
      for (int ni = 0; ni < 2; ++ni) {
        const int row = wc * 32 + ni * 16 + (lane & 15);
        bfr[ni] = *(const bf16x8*)(Bs + row * 64 + ((g ^ (row & 7)) * 8));
      }
#pragma unroll
      for (int mi = 0; mi < 2; ++mi)
#pragma unroll
        for (int ni = 0; ni < 2; ++ni)
          acc[mi][ni] = __builtin_amdgcn_mfma_f32_16x16x32_bf16(
              af[mi], bfr[ni], acc[mi][ni], 0, 0, 0);
    }
    __syncthreads();   // last one also protects the tbuf overlays
  }

  // Fused epilogue, 2 passes; pass mi uses its OWN [32][64] tbuf (As / Bs).
  const float LOG2E = 1.44269504f;
  const int jr = (lane >> 4) * 4;
  const int lc = lane & 15;
  f32x4 c0v[2], c1v[2];
  float cav[2];
#pragma unroll
  for (int ni = 0; ni < 2; ++ni) {
    const int cloc = wc * 32 + ni * 16 + lc;
    c0v[ni] = colcc[cloc];
    c1v[ni] = colxy[cloc];
    cav[ni] = c0v[ni][2] * c0v[ni][3];
  }

#pragma unroll
  for (int mi = 0; mi < 2; ++mi) {
    float* const tb = (mi == 0) ? (float*)As : (float*)Bs;   // [32][64]
#pragma unroll
    for (int j = 0; j < 4; ++j) {
      const int rloc = wr * 32 + mi * 16 + jr + j;
      const f32x4 r0 = rowcc[rloc];
      const f32x4 r1 = rowxy[rloc];
      const float ra = r0[2] * r0[3];
#pragma unroll
      for (int ni = 0; ni < 2; ++ni) {
        const f32x4 c0 = c0v[ni], c1 = c1v[ni];
        const float cc = fmaxf(acc[mi][ni][j], 0.0f);
        const float l1 = fabsf(r0[0] - c0[0]) + fabsf(r0[1] - c0[1]) +
                         fabsf(r0[2] - c0[2]) + fabsf(r0[3] - c0[3]);
        const float iwx = fminf(r1[2], c1[2]) - fmaxf(r1[0], c1[0]);
        const float iwy = fminf(r1[3], c1[3]) - fmaxf(r1[1], c1[1]);
        const float iw = fmaxf(iwx, 0.f);
        const float ih = fmaxf(iwy, 0.f);
        const float inter = iw * ih;
        const float uni = ra + cav[ni] - inter;
        const float ex = (r0[2] + c0[2]) - iwx;
        const float ey = (r0[3] + c0[3]) - iwy;
        const float earea = ex * ey;
        const float num = fmaf(uni, uni, inter * earea);
        const float Cv = fmaf(-num, __builtin_amdgcn_rcpf(uni * earea),
                              l1 + cc + 1.0f);
        const float sg = __builtin_amdgcn_rcpf(
            1.0f + __builtin_amdgcn_exp2f(-LOG2E * Cv));
        // local row wr*16 + jr + j, stride 64 (2-way on write = free).
        tb[(wr * 16 + jr + j) * 64 + wc * 32 + ni * 16 + lc] = sg;
      }
    }
    // lgkm-only block barrier: this pass's LDS writes visible; NT stores
    // keep streaming (never drained). No hazard with the other pass's buf.
    asm volatile("s_waitcnt lgkmcnt(0)" ::: "memory");
    __builtin_amdgcn_s_barrier();
    // Readback: thread t covers local row t>>4 (of 16), 16-B col-group
    // t&15, from BOTH wr-halves (global rows mi*16+r and 32+mi*16+r).
    {
      const int rch = t >> 4;                // 0..15
      const int c4 = (t & 15) * 4;           // 0..60
      const f32x4 v0 = *(const f32x4*)(tb + rch * 64 + c4);
      const f32x4 v1 = *(const f32x4*)(tb + (16 + rch) * 64 + c4);
      float* const dst = out + (size_t)(rowBase + mi * 16 + rch) * M_COLS
                         + colBase + c4;
      __builtin_nontemporal_store(v0, (f32x4*)dst);
      __builtin_nontemporal_store(v1, (f32x4*)(dst + 32 * M_COLS));
    }
    // No second barrier: pass 1 writes the OTHER buffer (no overwrite
    // hazard); its own pre-readback barrier orders its writes.
  }
}

extern "C" void kernel_launch(void* const* d_in, const int* in_sizes, int n_in,
                              void* d_out, int out_size, void* d_ws, size_t ws_size,
                              hipStream_t stream) {
  const float* logits = (const float*)d_in[0];   // [16,900,256]
  const float* pbox   = (const float*)d_in[1];   // [16,900,4]
  const float* embs   = (const float*)d_in[2];   // [1600,256]
  const float* tbox   = (const float*)d_in[3];   // [1600,4]
  float* out = (float*)d_out;                    // [16,900,1600]

  short* probB = (short*)d_ws;                         // 14400*256 bf16
  short* embB  = probB + (size_t)N_ROWS * KDIM;        // 1600*256 bf16

  prep_kernel<<<(N_ROWS + M_COLS) / 4, 256, 0, stream>>>(logits, embs, probB, embB);

  cost_kernel<<<NWG, 256, 0, stream>>>(probB, embB, pbox, tbox, out);
}

// Round 19
// 47.278 us; speedup vs baseline: 1.2737x; 1.0197x over previous
//
#include <hip/hip_runtime.h>

#define N_ROWS 14400
#define M_COLS 1600
#define KDIM   256
#define GRID_X 25           // 1600 / 64  (exact)
#define GRID_Y 225          // 14400 / 64 (exact)
#define NWG    (GRID_X * GRID_Y)   // 5625

typedef __attribute__((ext_vector_type(8))) short bf16x8;
typedef __attribute__((ext_vector_type(4))) float f32x4;

__device__ __forceinline__ short f2bf(float x) {
  union { float f; unsigned u; } v; v.f = x;
  unsigned r = v.u + 0x7FFFu + ((v.u >> 16) & 1u);   // RNE to bf16
  return (short)(r >> 16);
}

__device__ __forceinline__ void gload_lds16(const void* g, void* l) {
  __builtin_amdgcn_global_load_lds(
      (const __attribute__((address_space(1))) void*)g,
      (__attribute__((address_space(3))) void*)l, 16, 0, 0);
}

// One WAVE per row; lane handles 4 consecutive floats (float4 in, short4 out).
__global__ __launch_bounds__(256) void prep_kernel(
    const float* __restrict__ logits, const float* __restrict__ embs,
    short* __restrict__ probB, short* __restrict__ embB) {
  const int row = blockIdx.x * 4 + (threadIdx.x >> 6);
  const int lane = threadIdx.x & 63;
  if (row < N_ROWS) {
    const float4 x = ((const float4*)(logits + (size_t)row * KDIM))[lane];
    float s = x.x * x.x + x.y * x.y + x.z * x.z + x.w * x.w;
#pragma unroll
    for (int o = 32; o > 0; o >>= 1) s += __shfl_xor(s, o, 64);
    const float scale = __builtin_amdgcn_rsqf(s);
    short4 o4;
    o4.x = f2bf(x.x * scale); o4.y = f2bf(x.y * scale);
    o4.z = f2bf(x.z * scale); o4.w = f2bf(x.w * scale);
    ((short4*)(probB + (size_t)row * KDIM))[lane] = o4;
  } else {
    const int r = row - N_ROWS;   // grid sized exactly, no overflow
    const float4 x = ((const float4*)(embs + (size_t)r * KDIM))[lane];
    short4 o4;
    o4.x = f2bf(x.x); o4.y = f2bf(x.y); o4.z = f2bf(x.z); o4.w = f2bf(x.w);
    ((short4*)(embB + (size_t)r * KDIM))[lane] = o4;
  }
}

// 64x64 tile GEMM (bf16 MFMA) + fused bbox-L1 + GIoU + sigmoid epilogue.
// FINAL (r14, session best 47.5 us). Proven components:
// - acc[2][2] = 16 AGPR; 4 waves of 32x32; exact 64-tiling (zero guards).
// - Naive 4-phase K-loop at max residency. Eight schedule restructures
//   (r8/r10/r12/r13/r15/r16/r17 + r6) all lost to it: with K=256 short and
//   a fat epilogue, inter-block TLP beats every intra-block pipeline the
//   HIP compiler will emit.
// - LDS 20 KB; XOR-swizzled GEMM tiles (pre-swizzled global src granule +
//   swizzled read slot) -> 0 bank conflicts.
// - Epilogue: 2 passes, per-wr 16x68 tbuf overlay on dead As, lgkm-only
//   barriers (NT stores never drained), 256-B-coalesced dwordx4 NT stores
//   -> WRITE_SIZE exactly 90000 KB (zero amplification), FETCH ~7 MB.
// - Bijective XCD-aware block swizzle (m204).
// - No launch clamp (r2/r4/r10: forced VGPR<=64 always lost ~10us).
__global__ __launch_bounds__(256) void cost_kernel(
    const short* __restrict__ probB, const short* __restrict__ embB,
    const float* __restrict__ pbox, const float* __restrict__ tbox,
    float* __restrict__ out) {
  __shared__ short As[64 * 64];     // 8 KB; tbuf overlays in epilogue
  __shared__ short Bs[64 * 64];     // 8 KB
  __shared__ f32x4 rowcc[64], rowxy[64];   // 2 KB
  __shared__ f32x4 colcc[64], colxy[64];   // 2 KB

  const int t = threadIdx.x;
  const int lane = t & 63;
  const int wid = t >> 6;
  const int wr = wid >> 1;          // wave row 0..1 (32-row band)
  const int wc = wid & 1;           // wave col 0..1 (32-col band)

  // Bijective XCD swizzle (m204): 8 XCDs, NWG=5625 (q=703, r=1).
  const int orig = blockIdx.x;
  const int xcd = orig & 7;
  const int rem = orig >> 3;
  const int q = NWG >> 3, r = NWG & 7;
  const int wgid = (xcd < r ? xcd * (q + 1) : r * (q + 1) + (xcd - r) * q) + rem;
  const int bx = wgid % GRID_X;
  const int by = wgid / GRID_X;
  const int rowBase = by * 64;      // N (pred): always in-range (225*64)
  const int colBase = bx * 64;      // M (tgt):  always in-range (25*64)

  // Stage per-tile box data (no clamps: exact tiling).
  if (t < 64) {
    const float4 bb = ((const float4*)pbox)[rowBase + t];
    rowcc[t] = (f32x4){bb.x, bb.y, bb.z, bb.w};
    rowxy[t] = (f32x4){fmaf(-0.5f, bb.z, bb.x), fmaf(-0.5f, bb.w, bb.y),
                       fmaf(0.5f, bb.z, bb.x), fmaf(0.5f, bb.w, bb.y)};
  } else if (t < 128) {
    const int c = t - 64;
    const float4 bb = ((const float4*)tbox)[colBase + c];
    colcc[c] = (f32x4){bb.x, bb.y, bb.z, bb.w};
    colxy[c] = (f32x4){fmaf(-0.5f, bb.z, bb.x), fmaf(-0.5f, bb.w, bb.y),
                       fmaf(0.5f, bb.z, bb.x), fmaf(0.5f, bb.w, bb.y)};
  }

  f32x4 acc[2][2];
#pragma unroll
  for (int i = 0; i < 2; ++i)
#pragma unroll
    for (int j = 0; j < 2; ++j) acc[i][j] = (f32x4){0.f, 0.f, 0.f, 0.f};

  // Pre-swizzled source granule: lane l stages granule (l&7)^(l>>3); read
  // slot g^(row&7) sees linear data.
  const int swz = (lane & 7) ^ (lane >> 3);
  const int rbase = wid * 8 + (lane >> 3);   // staging row within 32-row group

  // K-loop: 4 tiles of BK=64.
  for (int kt = 0; kt < 4; ++kt) {
    const int k0 = kt * 64 + swz * 8;
#pragma unroll
    for (int i = 0; i < 2; ++i) {            // A: 64 rows
      const int gr = rowBase + i * 32 + rbase;
      gload_lds16(probB + (size_t)gr * KDIM + k0, As + (i * 32 + wid * 8) * 64);
    }
#pragma unroll
    for (int i = 0; i < 2; ++i) {            // B: 64 rows (cols)
      const int gc = colBase + i * 32 + rbase;
      gload_lds16(embB + (size_t)gc * KDIM + k0, Bs + (i * 32 + wid * 8) * 64);
    }
    __syncthreads();
#pragma unroll
    for (int kk = 0; kk < 2; ++kk) {
      bf16x8 af[2], bfr[2];
      const int g = kk * 4 + (lane >> 4);    // 16B granule index 0..7
#pragma unroll
      for (int mi = 0; mi < 2; ++mi) {
        const int row = wr * 32 + mi * 16 + (lane & 15);
        af[mi] = *(const bf16x8*)(As + row * 64 + ((g ^ (row & 7)) * 8));
      }
#pragma unroll
      for (int ni = 0; ni < 2; ++ni) {
        const int row = wc * 32 + ni * 16 + (lane & 15);
        bfr[ni] = *(const bf16x8*)(Bs + row * 64 + ((g ^ (row & 7)) * 8));
      }
#pragma unroll
      for (int mi = 0; mi < 2; ++mi)
#pragma unroll
        for (int ni = 0; ni < 2; ++ni)
          acc[mi][ni] = __builtin_amdgcn_mfma_f32_16x16x32_bf16(
              af[mi], bfr[ni], acc[mi][ni], 0, 0, 0);
    }
    __syncthreads();   // last one also protects the tbuf overlay
  }

  // Fused epilogue, 2 passes. Pass mi: each wave writes its 16-row chunk
  // into per-wr tbuf (16x68, 2-way banks) -> lgkm barrier -> all threads
  // read 2 f32x4 and NT-store 256-B coalesced lines -> barrier (pass 0).
  const float LOG2E = 1.44269504f;
  const int jr = (lane >> 4) * 4;
  const int lc = lane & 15;
  float* const tb = (float*)As + wr * 1088;      // this wave's 16x68 buffer
  f32x4 c0v[2], c1v[2];
  float cav[2];
#pragma unroll
  for (int ni = 0; ni < 2; ++ni) {
    const int cloc = wc * 32 + ni * 16 + lc;
    c0v[ni] = colcc[cloc];
    c1v[ni] = colxy[cloc];
    cav[ni] = c0v[ni][2] * c0v[ni][3];
  }

#pragma unroll
  for (int mi = 0; mi < 2; ++mi) {
#pragma unroll
    for (int j = 0; j < 4; ++j) {
      const int rloc = wr * 32 + mi * 16 + jr + j;
      const f32x4 r0 = rowcc[rloc];
      const f32x4 r1 = rowxy[rloc];
      const float ra = r0[2] * r0[3];
#pragma unroll
      for (int ni = 0; ni < 2; ++ni) {
        const f32x4 c0 = c0v[ni], c1 = c1v[ni];
        const float cc = fmaxf(acc[mi][ni][j], 0.0f);
        const float l1 = fabsf(r0[0] - c0[0]) + fabsf(r0[1] - c0[1]) +
                         fabsf(r0[2] - c0[2]) + fabsf(r0[3] - c0[3]);
        const float iwx = fminf(r1[2], c1[2]) - fmaxf(r1[0], c1[0]);
        const float iwy = fminf(r1[3], c1[3]) - fmaxf(r1[1], c1[1]);
        const float iw = fmaxf(iwx, 0.f);
        const float ih = fmaxf(iwy, 0.f);
        const float inter = iw * ih;
        const float uni = ra + cav[ni] - inter;
        const float ex = (r0[2] + c0[2]) - iwx;
        const float ey = (r0[3] + c0[3]) - iwy;
        const float earea = ex * ey;
        const float num = fmaf(uni, uni, inter * earea);
        const float Cv = fmaf(-num, __builtin_amdgcn_rcpf(uni * earea),
                              l1 + cc + 1.0f);
        const float sg = __builtin_amdgcn_rcpf(
            1.0f + __builtin_amdgcn_exp2f(-LOG2E * Cv));
        tb[(jr + j) * 68 + wc * 32 + ni * 16 + lc] = sg;
      }
    }
    // lgkm-only block barrier: LDS writes visible, NT stores keep streaming.
    asm volatile("s_waitcnt lgkmcnt(0)" ::: "memory");
    __builtin_amdgcn_s_barrier();
    // Readback: thread t covers row t>>4 (of 16), 16-B col-group t&15,
    // from BOTH wr-buffers (global rows mi*16+r and 32+mi*16+r).
    {
      const int rch = t >> 4;                // 0..15
      const int c4 = (t & 15) * 4;           // 0..60
      const f32x4 v0 = *(const f32x4*)((float*)As + rch * 68 + c4);
      const f32x4 v1 = *(const f32x4*)((float*)As + 1088 + rch * 68 + c4);
      float* const dst = out + (size_t)(rowBase + mi * 16 + rch) * M_COLS
                         + colBase + c4;
      __builtin_nontemporal_store(v0, (f32x4*)dst);
      __builtin_nontemporal_store(v1, (f32x4*)(dst + 32 * M_COLS));
    }
    if (mi == 0) {   // protect tbuf before pass 1 overwrites it
      asm volatile("s_waitcnt lgkmcnt(0)" ::: "memory");
      __builtin_amdgcn_s_barrier();
    }
  }
}

extern "C" void kernel_launch(void* const* d_in, const int* in_sizes, int n_in,
                              void* d_out, int out_size, void* d_ws, size_t ws_size,
                              hipStream_t stream) {
  const float* logits = (const float*)d_in[0];   // [16,900,256]
  const float* pbox   = (const float*)d_in[1];   // [16,900,4]
  const float* embs   = (const float*)d_in[2];   // [1600,256]
  const float* tbox   = (const float*)d_in[3];   // [1600,4]
  float* out = (float*)d_out;                    // [16,900,1600]

  short* probB = (short*)d_ws;                         // 14400*256 bf16
  short* embB  = probB + (size_t)N_ROWS * KDIM;        // 1600*256 bf16

  prep_kernel<<<(N_ROWS + M_COLS) / 4, 256, 0, stream>>>(logits, embs, probB, embB);

  cost_kernel<<<NWG, 256, 0, stream>>>(probB, embB, pbox, tbox, out);
}